// Round 5
// baseline (77.530 us; speedup 1.0000x reference)
//
#include <hip/hip_runtime.h>
#include <math.h>

#define BATCH 262144
#define N 8
#define BLK 64
#define NBLK (BATCH / BLK)   // 4096 single-wave blocks
#define NCMP 28              // odd-even network on 8 elems

typedef float v2f __attribute__((ext_vector_type(2)));

// Comparator schedule + per-ROW-PAIR support masks (union of the two rows'
// possibly-nonzero column sets BEFORE comparator k). P starts as I; when a
// comparator's columns are both outside the pair's support, the blend maps
// (0,0)->(0,0) and is skipped. Skipping is speed-only: kept blends are the
// full form, correct regardless of mask precision.
struct Net { int a[NCMP]; unsigned sup2[N / 2][NCMP]; };
constexpr Net make_net() {
    Net n{};
    int k = 0;
    for (int L = 0; L < N; ++L)
        for (int a = (L & 1); a < N - 1; a += 2)
            n.a[k++] = a;
    for (int r = 0; r < N / 2; ++r) {
        unsigned s = (1u << (2 * r)) | (1u << (2 * r + 1));
        for (int q = 0; q < NCMP; ++q) {
            n.sup2[r][q] = s;
            unsigned m = 3u << n.a[q];
            if (s & m) s |= m;
        }
    }
    return n;
}
constexpr Net NET = make_net();

// alpha(z) = 0.5 + atan(z)/pi. Deg-5 minimax atan on [0,1] (rel err ~1e-4,
// preserved through rcp arg-reduction) -> ~1e-4 rel err on log-domain loss
// terms vs the 1.18e-2 absolute output threshold.
__device__ __forceinline__ float cauchy_alpha(float z10) {
    float az  = __builtin_fabsf(z10);
    bool  big = az > 1.0f;
    float inv = __builtin_amdgcn_rcpf(az);
    float t   = big ? inv : az;
    float t2  = t * t;
    float p   = 0.1417796f;
    p = __builtin_fmaf(p, t2, -0.3258092f);
    p = __builtin_fmaf(p, t2, 0.9992150f);
    float at = p * t;
    float r  = big ? (1.5707963267948966f - at) : at;
    float sr = __builtin_copysignf(r, z10);
    return __builtin_fmaf(sr, 0.31830988618379067f, 0.5f);
}

// P stored as float2 row-pairs: p2[r][j] = (P[2r][j], P[2r+1][j]). Each
// comparator applies ONE alpha to all rows -> row-pair blends become
// v_pk_fma_f32 (dual-FP32 VOP3P: same 2-cycle issue, 2x work), halving the
// issue slots of the dominant op block.
__global__ __launch_bounds__(BLK, 4) void diffsort_loss_kernel(
    const float* __restrict__ pred,
    const float* __restrict__ labels,
    const float* __restrict__ rank_ema,
    float* __restrict__ partial)
{
    const int row = blockIdx.x * BLK + threadIdx.x;

    // tiny uniform ema table -> LDS
    __shared__ float ema[N];
    if (threadIdx.x < N) ema[threadIdx.x] = rank_ema[threadIdx.x];
    __syncthreads();

    // ---- vectorized row loads ----
    const float4* lp = (const float4*)(labels + (size_t)row * N);
    const float4* pp = (const float4*)(pred   + (size_t)row * N);
    float4 l0 = lp[0], l1 = lp[1];
    float4 p0 = pp[0], p1 = pp[1];
    float lab[N] = {l0.x, l0.y, l0.z, l0.w, l1.x, l1.y, l1.z, l1.w};
    float prd[N] = {p0.x, p0.y, p0.z, p0.w, p1.x, p1.y, p1.z, p1.w};

    // ---- rank_true via pairwise comparisons (stable argsort of -labels) ----
    int rt[N];
#pragma unroll
    for (int i = 0; i < N; ++i) rt[i] = 0;
#pragma unroll
    for (int i = 0; i < N; ++i)
#pragma unroll
        for (int j = i + 1; j < N; ++j) {
            unsigned c = lab[j] > lab[i];
            rt[i] += c;
            rt[j] += 1u - c;
        }

    // ---- x = rank_ema[rt] - pred  (= -shifted) ----
    float x[N];
#pragma unroll
    for (int i = 0; i < N; ++i)
        x[i] = ema[rt[i]] - prd[i];

    // ---- P as packed row-pairs, init to identity ----
    v2f p2[N / 2][N];
#pragma unroll
    for (int r = 0; r < N / 2; ++r)
#pragma unroll
        for (int j = 0; j < N; ++j) {
            v2f v;
            v.x = (j == 2 * r)     ? 1.0f : 0.0f;
            v.y = (j == 2 * r + 1) ? 1.0f : 0.0f;
            p2[r][j] = v;
        }

    // ---- odd-even network: x scalar, P row-pairs packed ----
#pragma unroll
    for (int k = 0; k < NCMP; ++k) {
        const int ia = NET.a[k], ib = ia + 1;
        const float a = x[ia], b = x[ib];
        const float z = b - a;
        const float alpha = cauchy_alpha(10.0f * z);
        x[ia] = __builtin_fmaf(-alpha, z, b);  // alpha*a + (1-alpha)*b
        x[ib] = __builtin_fmaf( alpha, z, a);  // (1-alpha)*a + alpha*b
        v2f al2; al2.x = alpha; al2.y = alpha;
#pragma unroll
        for (int r = 0; r < N / 2; ++r) {
            const bool live = ((NET.sup2[r][k] >> ia) | (NET.sup2[r][k] >> ib)) & 1u; // compile-time
            if (live) {
                const v2f ca = p2[r][ia], cb = p2[r][ib];
                const v2f d  = ca - cb;                       // v_pk_add (neg)
                p2[r][ia] = __builtin_elementwise_fma( al2, d, cb);  // v_pk_fma
                p2[r][ib] = __builtin_elementwise_fma(-al2, d, ca);  // v_pk_fma
            }
        }
    }

    // ---- loss, packed over row-pairs: gt row i one-hot at col rt[i];
    //      arg_i = p[h_i] * prod_{j!=h_i}(1-p[j]); per-entry -100 clips can't
    //      engage (entries are strict convex combos), single end-clamp. ----
    float s = 0.0f;
#pragma unroll
    for (int r = 0; r < N / 2; ++r) {
        const int h0 = rt[2 * r], h1 = rt[2 * r + 1];
        v2f arg; arg.x = 1.0f; arg.y = 1.0f;
#pragma unroll
        for (int j = 0; j < N; ++j) {
            const v2f pv = p2[r][j];
            v2f one; one.x = 1.0f; one.y = 1.0f;
            const v2f qv = one - pv;                  // v_pk_add
            v2f f;
            f.x = (h0 == j) ? pv.x : qv.x;
            f.y = (h1 == j) ? pv.y : qv.y;
            arg *= f;                                  // v_pk_mul
        }
        s += __logf(fmaxf(arg.x, 1e-37f));
        s += __logf(fmaxf(arg.y, 1e-37f));
    }

    // ---- wave(64) shuffle reduce -> one partial per wave-block ----
#pragma unroll
    for (int off = 32; off > 0; off >>= 1)
        s += __shfl_down(s, off);
    if (threadIdx.x == 0) partial[blockIdx.x] = s;
}

__global__ __launch_bounds__(256) void reduce_partials(
    const float* __restrict__ partial, float* __restrict__ out)
{
    float s = 0.0f;
#pragma unroll
    for (int k = 0; k < NBLK / 256; ++k)
        s += partial[threadIdx.x + k * 256];
#pragma unroll
    for (int off = 32; off > 0; off >>= 1)
        s += __shfl_down(s, off);

    __shared__ float wsum[4];
    const int lane = threadIdx.x & 63;
    const int wid  = threadIdx.x >> 6;
    if (lane == 0) wsum[wid] = s;
    __syncthreads();
    if (threadIdx.x == 0) {
        const float tot = wsum[0] + wsum[1] + wsum[2] + wsum[3];
        // loss = -sum / (B * n * n) = -sum / 16777216
        out[0] = -tot * (1.0f / 16777216.0f);
    }
}

extern "C" void kernel_launch(void* const* d_in, const int* in_sizes, int n_in,
                              void* d_out, int out_size, void* d_ws, size_t ws_size,
                              hipStream_t stream)
{
    const float* pred     = (const float*)d_in[0];
    const float* labels   = (const float*)d_in[1];
    const float* rank_ema = (const float*)d_in[2];
    float* out     = (float*)d_out;
    float* partial = (float*)d_ws;   // NBLK*4 = 16 KiB scratch

    diffsort_loss_kernel<<<NBLK, BLK, 0, stream>>>(pred, labels, rank_ema, partial);
    reduce_partials<<<1, 256, 0, stream>>>(partial, out);
}